// Round 1
// baseline (7195.036 us; speedup 1.0000x reference)
//
#include <hip/hip_runtime.h>
#include <math.h>

#define PX 4096         // 64*64 spatial
#define EPS 1e-5f

// ---------------------------------------------------------------------------
// ws layout (floats):
//   comb   [64 n][128 ch][4096]          (n = t*4+b; ch<64 = fwd h, >=64 = bwd h)
//   gates  [8 dirb][256 oc][4096]        (dirb = dir*4+b), reused every step
//   h      [8 dirb][64 ch][4096]
//   c      [8 dirb][64 ch][4096]
//   gnstat [16 s][2 dir][4 b][4 g][2]    (sum, sumsq) via atomicAdd
//   bnstat [64 oc][2]
// ---------------------------------------------------------------------------

// K1: gates = conv3x3(concat(x_t, h), W_dir) ; accumulate GN stats.
// grid: x = octile(16)*sp(8) = 128, y = dirb(8). block = 256.
// Each block: 16 oc x (16 rows x 32 cols) tile. Each thread: 16 oc x 2 px.
__global__ __launch_bounds__(256) void conv_step_kernel(
    const float* __restrict__ x, const float* __restrict__ hbuf,
    const float* __restrict__ Wf, const float* __restrict__ Wb,
    float* __restrict__ gates, float* __restrict__ gnstats, int s)
{
    const int dirb = blockIdx.y;
    const int dir = dirb >> 2, b = dirb & 3;
    const int octile = blockIdx.x >> 3;     // 0..15
    const int sp = blockIdx.x & 7;          // 4 row-tiles x 2 col-tiles
    const int sy = (sp >> 1) << 4;          // 0,16,32,48
    const int sx = (sp & 1) << 5;           // 0,32
    const int t = dir ? (15 - s) : s;
    const float* __restrict__ W = dir ? Wb : Wf;
    const float* __restrict__ xbase = x + ((size_t)(b * 16 + t) * 64) * PX;
    const float* __restrict__ hbase = hbuf + ((size_t)dirb * 64) * PX;

    __shared__ float in_s[16 * 18 * 34];    // 16 ic x (18 rows x 34 cols), 39168 B
    __shared__ float red[8];

    const int tid = threadIdx.x;
    const int ty = tid >> 4, tx = tid & 15;

    float acc0[16], acc1[16];
#pragma unroll
    for (int j = 0; j < 16; ++j) { acc0[j] = 0.f; acc1[j] = 0.f; }

    const float* __restrict__ wbase = W + (size_t)(octile * 16) * 1152;

    for (int c8 = 0; c8 < 8; ++c8) {
        const int ic0 = c8 * 16;
        const float* __restrict__ src = (c8 < 4)
            ? (xbase + (size_t)ic0 * PX)
            : (hbase + (size_t)(ic0 - 64) * PX);
        __syncthreads();
        for (int e = tid; e < 16 * 18 * 34; e += 256) {
            int ic = e / 612;
            int r = e - ic * 612;
            int ly = r / 34, lx = r - ly * 34;
            int gy = sy - 1 + ly, gx = sx - 1 + lx;
            float v = 0.f;
            if (gy >= 0 && gy < 64 && gx >= 0 && gx < 64)
                v = src[ic * PX + gy * 64 + gx];
            in_s[e] = v;
        }
        __syncthreads();

        const float* __restrict__ wc = wbase + ic0 * 9;  // block-uniform -> s_load
        for (int ic = 0; ic < 16; ++ic) {
            float a0[3][3], a1[3][3];
            const int base = ic * 612 + ty * 34 + tx;
#pragma unroll
            for (int dy = 0; dy < 3; ++dy)
#pragma unroll
                for (int dx = 0; dx < 3; ++dx) {
                    a0[dy][dx] = in_s[base + dy * 34 + dx];
                    a1[dy][dx] = in_s[base + dy * 34 + dx + 16];
                }
#pragma unroll
            for (int j = 0; j < 16; ++j) {
                const float* __restrict__ wj = wc + (size_t)j * 1152 + ic * 9;
#pragma unroll
                for (int dy = 0; dy < 3; ++dy)
#pragma unroll
                    for (int dx = 0; dx < 3; ++dx) {
                        float wv = wj[dy * 3 + dx];
                        acc0[j] += wv * a0[dy][dx];
                        acc1[j] += wv * a1[dy][dx];
                    }
            }
        }
    }

    // write gates + GN stats
    const int oy = sy + ty, ox = sx + tx;
    float s1 = 0.f, s2 = 0.f;
    size_t gb = ((size_t)dirb * 256 + octile * 16) * PX + oy * 64 + ox;
#pragma unroll
    for (int j = 0; j < 16; ++j) {
        float v0 = acc0[j], v1 = acc1[j];
        gates[gb + (size_t)j * PX] = v0;
        gates[gb + (size_t)j * PX + 16] = v1;
        s1 += v0 + v1;
        s2 += v0 * v0 + v1 * v1;
    }
    for (int off = 32; off; off >>= 1) {
        s1 += __shfl_down(s1, off);
        s2 += __shfl_down(s2, off);
    }
    int wid = tid >> 6;
    if ((tid & 63) == 0) { red[wid * 2] = s1; red[wid * 2 + 1] = s2; }
    __syncthreads();
    if (tid == 0) {
        float a = red[0] + red[2] + red[4] + red[6];
        float q = red[1] + red[3] + red[5] + red[7];
        int grp = octile >> 2;
        float* slot = gnstats + (((size_t)(s * 2 + dir) * 4 + b) * 4 + grp) * 2;
        atomicAdd(slot, a);
        atomicAdd(slot + 1, q);
    }
}

// K2: GN normalize + gate activations + LSTM state update + scatter h to comb.
__global__ __launch_bounds__(256) void point_kernel(
    const float* __restrict__ gates, const float* __restrict__ gnstats,
    const float* __restrict__ gnf_w, const float* __restrict__ gnf_b,
    const float* __restrict__ gnb_w, const float* __restrict__ gnb_b,
    float* __restrict__ hbuf, float* __restrict__ cbuf,
    float* __restrict__ comb, int s)
{
    int idx = blockIdx.x * 256 + threadIdx.x;   // 2^21 threads
    int px = idx & 4095;
    int ch = (idx >> 12) & 63;
    int b = (idx >> 18) & 3;
    int dir = idx >> 20;
    int dirb = dir * 4 + b;
    const float* __restrict__ gw = dir ? gnb_w : gnf_w;
    const float* __restrict__ gbv = dir ? gnb_b : gnf_b;
    const float* __restrict__ slotb = gnstats + ((size_t)(s * 2 + dir) * 4 + b) * 8;
    const float invN = 1.0f / 262144.0f;
    float vals[4];
#pragma unroll
    for (int g = 0; g < 4; ++g) {
        float sum = slotb[g * 2], sq = slotb[g * 2 + 1];
        float mean = sum * invN;
        float var = sq * invN - mean * mean;
        float rstd = rsqrtf(var + EPS);
        int oc = g * 64 + ch;
        float v = gates[((size_t)dirb * 256 + oc) * PX + px];
        vals[g] = (v - mean) * rstd * gw[oc] + gbv[oc];
    }
    float ig = 1.f / (1.f + __expf(-vals[0]));
    float fg = 1.f / (1.f + __expf(-vals[1]));
    float og = 1.f / (1.f + __expf(-vals[2]));
    float gg = tanhf(vals[3]);
    size_t hc = ((size_t)dirb * 64 + ch) * PX + px;
    float cold = cbuf[hc];
    float cnew = fg * cold + ig * gg;
    float hnew = og * tanhf(cnew);
    cbuf[hc] = cnew;
    hbuf[hc] = hnew;
    int t = dir ? (15 - s) : s;
    comb[((size_t)(t * 4 + b) * 128 + dir * 64 + ch) * PX + px] = hnew;
}

// K3: 1x1 fuse conv, BN stats only (fused values recomputed in K4).
// grid: x = q(4)*pc(4) = 16, y = n(64). block = 256.
__global__ __launch_bounds__(256) void fuse_stats_kernel(
    const float* __restrict__ comb, const float* __restrict__ Wfu,
    float* __restrict__ bnstats)
{
    int n = blockIdx.y;
    int q = blockIdx.x >> 2;
    int pc = blockIdx.x & 3;
    __shared__ float wl[16 * 128];
    __shared__ float redl[4][32];
    int tid = threadIdx.x;
    for (int e = tid; e < 2048; e += 256) wl[e] = Wfu[q * 2048 + e];
    __syncthreads();
    float s1[16], s2[16];
#pragma unroll
    for (int j = 0; j < 16; ++j) { s1[j] = 0.f; s2[j] = 0.f; }
    const float* __restrict__ cb = comb + (size_t)n * 128 * PX;
    for (int i = 0; i < 4; ++i) {
        int px = pc * 1024 + i * 256 + tid;
        float f[16];
#pragma unroll
        for (int j = 0; j < 16; ++j) f[j] = 0.f;
        for (int ic = 0; ic < 128; ++ic) {
            float v = cb[(size_t)ic * PX + px];
#pragma unroll
            for (int j = 0; j < 16; ++j) f[j] += wl[j * 128 + ic] * v;
        }
#pragma unroll
        for (int j = 0; j < 16; ++j) { s1[j] += f[j]; s2[j] += f[j] * f[j]; }
    }
    int lane = tid & 63, wid = tid >> 6;
#pragma unroll
    for (int j = 0; j < 16; ++j) {
        float a = s1[j], qq = s2[j];
        for (int off = 32; off; off >>= 1) {
            a += __shfl_down(a, off);
            qq += __shfl_down(qq, off);
        }
        if (lane == 0) { redl[wid][j] = a; redl[wid][16 + j] = qq; }
    }
    __syncthreads();
    if (tid < 16) {
        float a = redl[0][tid] + redl[1][tid] + redl[2][tid] + redl[3][tid];
        float qq = redl[0][16 + tid] + redl[1][16 + tid] + redl[2][16 + tid] + redl[3][16 + tid];
        atomicAdd(bnstats + (q * 16 + tid) * 2, a);
        atomicAdd(bnstats + (q * 16 + tid) * 2 + 1, qq);
    }
}

// K4: recompute 1x1 fuse conv, apply BN + ReLU, write transposed output.
__global__ __launch_bounds__(256) void bn_apply_kernel(
    const float* __restrict__ comb, const float* __restrict__ Wfu,
    const float* __restrict__ bnstats, const float* __restrict__ bn_w,
    const float* __restrict__ bn_b, float* __restrict__ out)
{
    int n = blockIdx.y;
    int q = blockIdx.x >> 2;
    int pc = blockIdx.x & 3;
    int tt = n >> 2, b = n & 3;
    __shared__ float wl[16 * 128];
    __shared__ float mb[16], rb[16], sw[16], sb[16];
    int tid = threadIdx.x;
    for (int e = tid; e < 2048; e += 256) wl[e] = Wfu[q * 2048 + e];
    if (tid < 16) {
        int oc = q * 16 + tid;
        const float invN = 1.0f / 262144.0f;
        float mean = bnstats[oc * 2] * invN;
        float var = bnstats[oc * 2 + 1] * invN - mean * mean;
        mb[tid] = mean;
        rb[tid] = rsqrtf(var + EPS);
        sw[tid] = bn_w[oc];
        sb[tid] = bn_b[oc];
    }
    __syncthreads();
    const float* __restrict__ cb = comb + (size_t)n * 128 * PX;
    float* __restrict__ ob = out + ((size_t)(b * 16 + tt) * 64 + q * 16) * PX;
    for (int i = 0; i < 4; ++i) {
        int px = pc * 1024 + i * 256 + tid;
        float f[16];
#pragma unroll
        for (int j = 0; j < 16; ++j) f[j] = 0.f;
        for (int ic = 0; ic < 128; ++ic) {
            float v = cb[(size_t)ic * PX + px];
#pragma unroll
            for (int j = 0; j < 16; ++j) f[j] += wl[j * 128 + ic] * v;
        }
#pragma unroll
        for (int j = 0; j < 16; ++j) {
            float o = (f[j] - mb[j]) * rb[j] * sw[j] + sb[j];
            ob[(size_t)j * PX + px] = fmaxf(o, 0.f);
        }
    }
}

extern "C" void kernel_launch(void* const* d_in, const int* in_sizes, int n_in,
                              void* d_out, int out_size, void* d_ws, size_t ws_size,
                              hipStream_t stream) {
    const float* x     = (const float*)d_in[0];   // [4,16,64,64,64]
    const float* Wf    = (const float*)d_in[1];   // [256,128,3,3]
    const float* gnf_w = (const float*)d_in[2];
    const float* gnf_b = (const float*)d_in[3];
    const float* Wb    = (const float*)d_in[4];
    const float* gnb_w = (const float*)d_in[5];
    const float* gnb_b = (const float*)d_in[6];
    const float* Wfu   = (const float*)d_in[7];   // [64,128,1,1]
    const float* bn_w  = (const float*)d_in[8];
    const float* bn_b  = (const float*)d_in[9];
    float* out = (float*)d_out;

    float* ws      = (float*)d_ws;
    float* comb    = ws;                          // 33,554,432 floats
    float* gates   = comb + 33554432ll;           //  8,388,608
    float* hbuf    = gates + 8388608ll;           //  2,097,152
    float* cbuf    = hbuf + 2097152ll;            //  2,097,152
    float* gnstats = cbuf + 2097152ll;            //  1,024
    float* bnstats = gnstats + 1024;              //  128
    // total ws use: 184,553,984 bytes

    // zero h, c, gn stats, bn stats (contiguous tail region)
    hipMemsetAsync(hbuf, 0, (size_t)(2097152ll * 2 + 1024 + 128) * 4, stream);

    for (int s = 0; s < 16; ++s) {
        conv_step_kernel<<<dim3(128, 8), 256, 0, stream>>>(
            x, hbuf, Wf, Wb, gates, gnstats, s);
        point_kernel<<<8192, 256, 0, stream>>>(
            gates, gnstats, gnf_w, gnf_b, gnb_w, gnb_b, hbuf, cbuf, comb, s);
    }
    fuse_stats_kernel<<<dim3(16, 64), 256, 0, stream>>>(comb, Wfu, bnstats);
    bn_apply_kernel<<<dim3(16, 64), 256, 0, stream>>>(comb, Wfu, bnstats, bn_w, bn_b, out);
}

// Round 2
// 1924.554 us; speedup vs baseline: 3.7385x; 3.7385x over previous
//
#include <hip/hip_runtime.h>
#include <math.h>

#define PX 4096         // 64*64 spatial
#define EPS 1e-5f

typedef __attribute__((ext_vector_type(8))) __bf16 bf16x8;
typedef __attribute__((ext_vector_type(4))) float f32x4;

static __device__ __forceinline__ unsigned short f2b(float f) {
    unsigned int u = __float_as_uint(f);
    u += 0x7FFFu + ((u >> 16) & 1u);     // RTNE
    return (unsigned short)(u >> 16);
}

// ---------------------------------------------------------------------------
// ws layout (floats):
//   comb    [64 n][128 ch][4096]
//   gates   [8 dirb][256 oc][4096]
//   h       [8 dirb][64 ch][4096]
//   c       [8 dirb][64 ch][4096]
//   gnstat  [16 s][2 dir][4 b][4 g][2]
//   bnstat  [64 oc][2]
//   W2      bf16 [2 dir][9 tap][256 oc][128 ic]   (589,824 ushorts)
// ---------------------------------------------------------------------------

// Pre-convert conv weights to bf16 in [dir][tap][oc][ic] layout.
__global__ __launch_bounds__(256) void wconv_kernel(
    const float* __restrict__ Wf, const float* __restrict__ Wb,
    unsigned short* __restrict__ W2)
{
    int idx = blockIdx.x * 256 + threadIdx.x;
    if (idx >= 589824) return;
    int ic = idx & 127;
    int oc = (idx >> 7) & 255;
    int rest = idx >> 15;           // dir*9 + tap
    int tap = rest % 9;
    int dir = rest / 9;
    const float* __restrict__ W = dir ? Wb : Wf;
    W2[idx] = f2b(W[((size_t)oc * 128 + ic) * 9 + tap]);
}

// K1: implicit-GEMM conv via MFMA.
// grid x = ocblk(4)*pxtile(16) = 64, y = dirb(8). block = 256 (4 waves).
// Block: 64 oc x (8 rows x 32 cols). Wave: 64 oc x 64 px (4x4 fragments).
__global__ __launch_bounds__(256) void conv_mfma_kernel(
    const float* __restrict__ x, const float* __restrict__ hbuf,
    const unsigned short* __restrict__ W2,
    float* __restrict__ gates, float* __restrict__ gnstats, int s)
{
    const int dirb = blockIdx.y;
    const int dir = dirb >> 2, b = dirb & 3;
    const int ocblk = blockIdx.x >> 4;
    const int pxt = blockIdx.x & 15;
    const int py0 = (pxt >> 1) * 8;       // 8-row tile
    const int pxc0 = (pxt & 1) * 32;      // 32-col tile
    const int t = dir ? (15 - s) : s;

    const float* __restrict__ xbase = x + ((size_t)(b * 16 + t) * 64) * PX;
    const float* __restrict__ hbase = hbuf + ((size_t)dirb * 64) * PX;

    __shared__ unsigned short Wl[9 * 64 * 32];    // 36,864 B  (swizzled)
    __shared__ unsigned short in_s[340 * 32];     // 21,760 B  (swizzled)
    __shared__ float red[8];

    const int tid = threadIdx.x;
    const int w = tid >> 6;
    const int l = tid & 63;
    const int l15 = l & 15;
    const int l4 = l >> 4;

    f32x4 acc[4][4];
#pragma unroll
    for (int i = 0; i < 4; ++i)
#pragma unroll
        for (int j = 0; j < 4; ++j)
            acc[i][j] = (f32x4){0.f, 0.f, 0.f, 0.f};

    for (int icblk = 0; icblk < 4; ++icblk) {
        __syncthreads();
        // ---- stage weights: 9 tap x 64 oc x 32 ic (XOR-swizzled 16B slots)
        {
            const unsigned short* __restrict__ wg = W2
                + ((size_t)(dir * 9) * 256 + (size_t)ocblk * 64) * 128 + icblk * 32;
#pragma unroll
            for (int it = 0; it < 18; ++it) {
                int idx = tid + it * 256;            // 4608 = 9*64*8 quads
                int icq = idx & 7;
                int oc = (idx >> 3) & 63;
                int tap = idx >> 9;
                uint2 v = *reinterpret_cast<const uint2*>(
                    wg + ((size_t)tap * 256 + oc) * 128 + icq * 4);
                int woff = tap * 2048 + oc * 32
                         + (((icq >> 1) ^ ((oc >> 1) & 3)) * 8) + (icq & 1) * 4;
                *reinterpret_cast<uint2*>(&Wl[woff]) = v;
            }
        }
        // ---- stage input halo tile: 340 px (10x34) x 32 ic
        {
            const float* __restrict__ src = (icblk < 2)
                ? (xbase + (size_t)(icblk * 32) * PX)
                : (hbase + (size_t)((icblk - 2) * 32) * PX);
#pragma unroll
            for (int it = 0; it < 11; ++it) {
                int idx = tid + it * 256;            // 2720 = 340*8 quads
                if (idx < 2720) {
                    int icq = idx & 7;
                    int pl = idx >> 3;
                    int row = (pl * 241) >> 13;      // pl / 34 for pl<340
                    int col = pl - row * 34;
                    int gy = py0 - 1 + row;
                    int gx = pxc0 - 1 + col;
                    bool valid = ((unsigned)gy < 64u) && ((unsigned)gx < 64u);
                    const float* sp = src + (size_t)(icq * 4) * PX + gy * 64 + gx;
                    float f0 = valid ? sp[0] : 0.f;
                    float f1 = valid ? sp[PX] : 0.f;
                    float f2 = valid ? sp[2 * PX] : 0.f;
                    float f3 = valid ? sp[3 * PX] : 0.f;
                    unsigned int lo = (unsigned int)f2b(f0) | ((unsigned int)f2b(f1) << 16);
                    unsigned int hi = (unsigned int)f2b(f2) | ((unsigned int)f2b(f3) << 16);
                    int woff = pl * 32
                             + (((icq >> 1) ^ ((pl >> 1) & 3)) * 8) + (icq & 1) * 4;
                    *reinterpret_cast<uint2*>(&in_s[woff]) = make_uint2(lo, hi);
                }
            }
        }
        __syncthreads();

        // ---- 9 taps x 16 MFMA
#pragma unroll
        for (int tap = 0; tap < 9; ++tap) {
            const int dy = tap / 3, dx = tap % 3;
            bf16x8 av[4], bv[4];
#pragma unroll
            for (int mi = 0; mi < 4; ++mi) {
                int oc = mi * 16 + l15;
                int aoff = tap * 2048 + oc * 32 + ((l4 ^ ((oc >> 1) & 3)) * 8);
                av[mi] = *reinterpret_cast<const bf16x8*>(&Wl[aoff]);
            }
#pragma unroll
            for (int ni = 0; ni < 4; ++ni) {
                int nr = ni >> 1, nc = ni & 1;
                int pl = (2 * w + nr + dy) * 34 + nc * 16 + l15 + dx;
                int boff = pl * 32 + ((l4 ^ ((pl >> 1) & 3)) * 8);
                bv[ni] = *reinterpret_cast<const bf16x8*>(&in_s[boff]);
            }
#pragma unroll
            for (int mi = 0; mi < 4; ++mi)
#pragma unroll
                for (int ni = 0; ni < 4; ++ni)
                    acc[mi][ni] = __builtin_amdgcn_mfma_f32_16x16x32_bf16(
                        av[mi], bv[ni], acc[mi][ni], 0, 0, 0);
        }
    }

    // ---- epilogue: write gates (fp32) + GN partial stats
    float s1 = 0.f, s2 = 0.f;
    float* __restrict__ gbase = gates + ((size_t)dirb * 256 + (size_t)ocblk * 64) * PX;
#pragma unroll
    for (int mi = 0; mi < 4; ++mi)
#pragma unroll
        for (int ni = 0; ni < 4; ++ni) {
            int nr = ni >> 1, nc = ni & 1;
            int px = (py0 + 2 * w + nr) * 64 + pxc0 + nc * 16 + l15;
#pragma unroll
            for (int j = 0; j < 4; ++j) {
                float v = acc[mi][ni][j];
                int oc = mi * 16 + l4 * 4 + j;
                gbase[(size_t)oc * PX + px] = v;
                s1 += v;
                s2 += v * v;
            }
        }
    for (int off = 32; off; off >>= 1) {
        s1 += __shfl_down(s1, off);
        s2 += __shfl_down(s2, off);
    }
    if (l == 0) { red[w * 2] = s1; red[w * 2 + 1] = s2; }
    __syncthreads();
    if (tid == 0) {
        float a = red[0] + red[2] + red[4] + red[6];
        float q = red[1] + red[3] + red[5] + red[7];
        float* slot = gnstats + (((size_t)(s * 2 + dir) * 4 + b) * 4 + ocblk) * 2;
        atomicAdd(slot, a);
        atomicAdd(slot + 1, q);
    }
}

// K2: GN normalize + gate activations + LSTM state update + scatter h to comb.
__global__ __launch_bounds__(256) void point_kernel(
    const float* __restrict__ gates, const float* __restrict__ gnstats,
    const float* __restrict__ gnf_w, const float* __restrict__ gnf_b,
    const float* __restrict__ gnb_w, const float* __restrict__ gnb_b,
    float* __restrict__ hbuf, float* __restrict__ cbuf,
    float* __restrict__ comb, int s)
{
    int idx = blockIdx.x * 256 + threadIdx.x;   // 2^21 threads
    int px = idx & 4095;
    int ch = (idx >> 12) & 63;
    int b = (idx >> 18) & 3;
    int dir = idx >> 20;
    int dirb = dir * 4 + b;
    const float* __restrict__ gw = dir ? gnb_w : gnf_w;
    const float* __restrict__ gbv = dir ? gnb_b : gnf_b;
    const float* __restrict__ slotb = gnstats + ((size_t)(s * 2 + dir) * 4 + b) * 8;
    const float invN = 1.0f / 262144.0f;
    float vals[4];
#pragma unroll
    for (int g = 0; g < 4; ++g) {
        float sum = slotb[g * 2], sq = slotb[g * 2 + 1];
        float mean = sum * invN;
        float var = sq * invN - mean * mean;
        float rstd = rsqrtf(var + EPS);
        int oc = g * 64 + ch;
        float v = gates[((size_t)dirb * 256 + oc) * PX + px];
        vals[g] = (v - mean) * rstd * gw[oc] + gbv[oc];
    }
    float ig = 1.f / (1.f + __expf(-vals[0]));
    float fg = 1.f / (1.f + __expf(-vals[1]));
    float og = 1.f / (1.f + __expf(-vals[2]));
    float gg = tanhf(vals[3]);
    size_t hc = ((size_t)dirb * 64 + ch) * PX + px;
    float cold = cbuf[hc];
    float cnew = fg * cold + ig * gg;
    float hnew = og * tanhf(cnew);
    cbuf[hc] = cnew;
    hbuf[hc] = hnew;
    int t = dir ? (15 - s) : s;
    comb[((size_t)(t * 4 + b) * 128 + dir * 64 + ch) * PX + px] = hnew;
}

// K3: 1x1 fuse conv, BN stats only.
__global__ __launch_bounds__(256) void fuse_stats_kernel(
    const float* __restrict__ comb, const float* __restrict__ Wfu,
    float* __restrict__ bnstats)
{
    int n = blockIdx.y;
    int q = blockIdx.x >> 2;
    int pc = blockIdx.x & 3;
    __shared__ float wl[16 * 128];
    __shared__ float redl[4][32];
    int tid = threadIdx.x;
    for (int e = tid; e < 2048; e += 256) wl[e] = Wfu[q * 2048 + e];
    __syncthreads();
    float s1[16], s2[16];
#pragma unroll
    for (int j = 0; j < 16; ++j) { s1[j] = 0.f; s2[j] = 0.f; }
    const float* __restrict__ cb = comb + (size_t)n * 128 * PX;
    for (int i = 0; i < 4; ++i) {
        int px = pc * 1024 + i * 256 + tid;
        float f[16];
#pragma unroll
        for (int j = 0; j < 16; ++j) f[j] = 0.f;
        for (int ic = 0; ic < 128; ++ic) {
            float v = cb[(size_t)ic * PX + px];
#pragma unroll
            for (int j = 0; j < 16; ++j) f[j] += wl[j * 128 + ic] * v;
        }
#pragma unroll
        for (int j = 0; j < 16; ++j) { s1[j] += f[j]; s2[j] += f[j] * f[j]; }
    }
    int lane = tid & 63, wid = tid >> 6;
#pragma unroll
    for (int j = 0; j < 16; ++j) {
        float a = s1[j], qq = s2[j];
        for (int off = 32; off; off >>= 1) {
            a += __shfl_down(a, off);
            qq += __shfl_down(qq, off);
        }
        if (lane == 0) { redl[wid][j] = a; redl[wid][16 + j] = qq; }
    }
    __syncthreads();
    if (tid < 16) {
        float a = redl[0][tid] + redl[1][tid] + redl[2][tid] + redl[3][tid];
        float qq = redl[0][16 + tid] + redl[1][16 + tid] + redl[2][16 + tid] + redl[3][16 + tid];
        atomicAdd(bnstats + (q * 16 + tid) * 2, a);
        atomicAdd(bnstats + (q * 16 + tid) * 2 + 1, qq);
    }
}

// K4: recompute 1x1 fuse conv, apply BN + ReLU, write transposed output.
__global__ __launch_bounds__(256) void bn_apply_kernel(
    const float* __restrict__ comb, const float* __restrict__ Wfu,
    const float* __restrict__ bnstats, const float* __restrict__ bn_w,
    const float* __restrict__ bn_b, float* __restrict__ out)
{
    int n = blockIdx.y;
    int q = blockIdx.x >> 2;
    int pc = blockIdx.x & 3;
    int tt = n >> 2, b = n & 3;
    __shared__ float wl[16 * 128];
    __shared__ float mb[16], rb[16], sw[16], sb[16];
    int tid = threadIdx.x;
    for (int e = tid; e < 2048; e += 256) wl[e] = Wfu[q * 2048 + e];
    if (tid < 16) {
        int oc = q * 16 + tid;
        const float invN = 1.0f / 262144.0f;
        float mean = bnstats[oc * 2] * invN;
        float var = bnstats[oc * 2 + 1] * invN - mean * mean;
        mb[tid] = mean;
        rb[tid] = rsqrtf(var + EPS);
        sw[tid] = bn_w[oc];
        sb[tid] = bn_b[oc];
    }
    __syncthreads();
    const float* __restrict__ cb = comb + (size_t)n * 128 * PX;
    float* __restrict__ ob = out + ((size_t)(b * 16 + tt) * 64 + q * 16) * PX;
    for (int i = 0; i < 4; ++i) {
        int px = pc * 1024 + i * 256 + tid;
        float f[16];
#pragma unroll
        for (int j = 0; j < 16; ++j) f[j] = 0.f;
        for (int ic = 0; ic < 128; ++ic) {
            float v = cb[(size_t)ic * PX + px];
#pragma unroll
            for (int j = 0; j < 16; ++j) f[j] += wl[j * 128 + ic] * v;
        }
#pragma unroll
        for (int j = 0; j < 16; ++j) {
            float o = (f[j] - mb[j]) * rb[j] * sw[j] + sb[j];
            ob[(size_t)j * PX + px] = fmaxf(o, 0.f);
        }
    }
}

extern "C" void kernel_launch(void* const* d_in, const int* in_sizes, int n_in,
                              void* d_out, int out_size, void* d_ws, size_t ws_size,
                              hipStream_t stream) {
    const float* x     = (const float*)d_in[0];
    const float* Wf    = (const float*)d_in[1];
    const float* gnf_w = (const float*)d_in[2];
    const float* gnf_b = (const float*)d_in[3];
    const float* Wb    = (const float*)d_in[4];
    const float* gnb_w = (const float*)d_in[5];
    const float* gnb_b = (const float*)d_in[6];
    const float* Wfu   = (const float*)d_in[7];
    const float* bn_w  = (const float*)d_in[8];
    const float* bn_b  = (const float*)d_in[9];
    float* out = (float*)d_out;

    float* ws      = (float*)d_ws;
    float* comb    = ws;                          // 33,554,432 floats
    float* gates   = comb + 33554432ll;           //  8,388,608
    float* hbuf    = gates + 8388608ll;           //  2,097,152
    float* cbuf    = hbuf + 2097152ll;            //  2,097,152
    float* gnstats = cbuf + 2097152ll;            //  1,024
    float* bnstats = gnstats + 1024;              //  128
    unsigned short* W2 = (unsigned short*)(bnstats + 128);  // 589,824 ushorts

    // zero h, c, gn stats, bn stats
    hipMemsetAsync(hbuf, 0, (size_t)(2097152ll * 2 + 1024 + 128) * 4, stream);

    wconv_kernel<<<2304, 256, 0, stream>>>(Wf, Wb, W2);

    for (int s = 0; s < 16; ++s) {
        conv_mfma_kernel<<<dim3(64, 8), 256, 0, stream>>>(
            x, hbuf, W2, gates, gnstats, s);
        point_kernel<<<8192, 256, 0, stream>>>(
            gates, gnstats, gnf_w, gnf_b, gnb_w, gnb_b, hbuf, cbuf, comb, s);
    }
    fuse_stats_kernel<<<dim3(16, 64), 256, 0, stream>>>(comb, Wfu, bnstats);
    bn_apply_kernel<<<dim3(16, 64), 256, 0, stream>>>(comb, Wfu, bnstats, bn_w, bn_b, out);
}

// Round 3
// 1220.656 us; speedup vs baseline: 5.8944x; 1.5767x over previous
//
#include <hip/hip_runtime.h>
#include <math.h>

#define PX 4096         // 64*64 spatial
#define EPS 1e-5f

typedef __attribute__((ext_vector_type(8))) __bf16 bf16x8;
typedef __attribute__((ext_vector_type(4))) float f32x4;

static __device__ __forceinline__ unsigned short f2b(float f) {
    unsigned int u = __float_as_uint(f);
    u += 0x7FFFu + ((u >> 16) & 1u);     // RTNE
    return (unsigned short)(u >> 16);
}
static __device__ __forceinline__ float b2f(unsigned short u) {
    return __uint_as_float((unsigned int)u << 16);
}
static __device__ __forceinline__ float rcpf(float x) {
    return __builtin_amdgcn_rcpf(x);
}

// ---------------------------------------------------------------------------
// ws layout (float units):
//   comb_t  bf16 [64 n][4096 px][128 ic]      16,777,216 f
//   gatesb  bf16 [8 dirb][256 oc][4096 px]     4,194,304 f
//   hbuf    f32  [8 dirb][64 ch][4096]         2,097,152 f
//   cbuf    f32  [8 dirb][64 ch][4096]         2,097,152 f
//   gnstat  f32  [16 s][2 dir][4 b][4 g][2]        1,024 f
//   bnparts f32  [8 part][64 oc][2]                1,024 f
//   W2      bf16 [2 dir][9 tap][256 oc][128 ic]  294,912 f
//   wfrag   bf16 [4 ocb][4 icblk][64 l][8 j]       4,096 f
// ---------------------------------------------------------------------------

__global__ __launch_bounds__(256) void wconv_kernel(
    const float* __restrict__ Wf, const float* __restrict__ Wb,
    unsigned short* __restrict__ W2)
{
    int idx = blockIdx.x * 256 + threadIdx.x;
    if (idx >= 589824) return;
    int ic = idx & 127;
    int oc = (idx >> 7) & 255;
    int rest = idx >> 15;           // dir*9 + tap
    int tap = rest % 9;
    int dir = rest / 9;
    const float* __restrict__ W = dir ? Wb : Wf;
    W2[idx] = f2b(W[((size_t)oc * 128 + ic) * 9 + tap]);
}

// Pack Wfu into MFMA B-fragment order: [ocb][icblk][lane][j]
__global__ __launch_bounds__(256) void wfu_pack_kernel(
    const float* __restrict__ Wfu, unsigned short* __restrict__ wfrag)
{
    int idx = blockIdx.x * 256 + threadIdx.x;
    if (idx >= 8192) return;
    int j = idx & 7;
    int l = (idx >> 3) & 63;
    int icblk = (idx >> 9) & 3;
    int ocb = idx >> 11;
    int oc = ocb * 16 + (l & 15);
    int ic = icblk * 32 + (l >> 4) * 8 + j;
    wfrag[idx] = f2b(Wfu[oc * 128 + ic]);
}

// K1: implicit-GEMM conv via MFMA (as round 2), gates stored bf16.
__global__ __launch_bounds__(256) void conv_mfma_kernel(
    const float* __restrict__ x, const float* __restrict__ hbuf,
    const unsigned short* __restrict__ W2,
    unsigned short* __restrict__ gatesb, float* __restrict__ gnstats, int s)
{
    const int dirb = blockIdx.y;
    const int dir = dirb >> 2, b = dirb & 3;
    const int ocblk = blockIdx.x >> 4;
    const int pxt = blockIdx.x & 15;
    const int py0 = (pxt >> 1) * 8;
    const int pxc0 = (pxt & 1) * 32;
    const int t = dir ? (15 - s) : s;

    const float* __restrict__ xbase = x + ((size_t)(b * 16 + t) * 64) * PX;
    const float* __restrict__ hbase = hbuf + ((size_t)dirb * 64) * PX;

    __shared__ unsigned short Wl[9 * 64 * 32];
    __shared__ unsigned short in_s[340 * 32];
    __shared__ float red[8];

    const int tid = threadIdx.x;
    const int w = tid >> 6;
    const int l = tid & 63;
    const int l15 = l & 15;
    const int l4 = l >> 4;

    f32x4 acc[4][4];
#pragma unroll
    for (int i = 0; i < 4; ++i)
#pragma unroll
        for (int j = 0; j < 4; ++j)
            acc[i][j] = (f32x4){0.f, 0.f, 0.f, 0.f};

    for (int icblk = 0; icblk < 4; ++icblk) {
        __syncthreads();
        {
            const unsigned short* __restrict__ wg = W2
                + ((size_t)(dir * 9) * 256 + (size_t)ocblk * 64) * 128 + icblk * 32;
#pragma unroll
            for (int it = 0; it < 18; ++it) {
                int idx = tid + it * 256;
                int icq = idx & 7;
                int oc = (idx >> 3) & 63;
                int tap = idx >> 9;
                uint2 v = *reinterpret_cast<const uint2*>(
                    wg + ((size_t)tap * 256 + oc) * 128 + icq * 4);
                int woff = tap * 2048 + oc * 32
                         + (((icq >> 1) ^ ((oc >> 1) & 3)) * 8) + (icq & 1) * 4;
                *reinterpret_cast<uint2*>(&Wl[woff]) = v;
            }
        }
        {
            const float* __restrict__ src = (icblk < 2)
                ? (xbase + (size_t)(icblk * 32) * PX)
                : (hbase + (size_t)((icblk - 2) * 32) * PX);
#pragma unroll
            for (int it = 0; it < 11; ++it) {
                int idx = tid + it * 256;
                if (idx < 2720) {
                    int icq = idx & 7;
                    int pl = idx >> 3;
                    int row = (pl * 241) >> 13;
                    int col = pl - row * 34;
                    int gy = py0 - 1 + row;
                    int gx = pxc0 - 1 + col;
                    bool valid = ((unsigned)gy < 64u) && ((unsigned)gx < 64u);
                    const float* sp = src + (size_t)(icq * 4) * PX + gy * 64 + gx;
                    float f0 = valid ? sp[0] : 0.f;
                    float f1 = valid ? sp[PX] : 0.f;
                    float f2 = valid ? sp[2 * PX] : 0.f;
                    float f3 = valid ? sp[3 * PX] : 0.f;
                    unsigned int lo = (unsigned int)f2b(f0) | ((unsigned int)f2b(f1) << 16);
                    unsigned int hi = (unsigned int)f2b(f2) | ((unsigned int)f2b(f3) << 16);
                    int woff = pl * 32
                             + (((icq >> 1) ^ ((pl >> 1) & 3)) * 8) + (icq & 1) * 4;
                    *reinterpret_cast<uint2*>(&in_s[woff]) = make_uint2(lo, hi);
                }
            }
        }
        __syncthreads();

#pragma unroll
        for (int tap = 0; tap < 9; ++tap) {
            const int dy = tap / 3, dx = tap % 3;
            bf16x8 av[4], bv[4];
#pragma unroll
            for (int mi = 0; mi < 4; ++mi) {
                int oc = mi * 16 + l15;
                int aoff = tap * 2048 + oc * 32 + ((l4 ^ ((oc >> 1) & 3)) * 8);
                av[mi] = *reinterpret_cast<const bf16x8*>(&Wl[aoff]);
            }
#pragma unroll
            for (int ni = 0; ni < 4; ++ni) {
                int nr = ni >> 1, nc = ni & 1;
                int pl = (2 * w + nr + dy) * 34 + nc * 16 + l15 + dx;
                int boff = pl * 32 + ((l4 ^ ((pl >> 1) & 3)) * 8);
                bv[ni] = *reinterpret_cast<const bf16x8*>(&in_s[boff]);
            }
#pragma unroll
            for (int mi = 0; mi < 4; ++mi)
#pragma unroll
                for (int ni = 0; ni < 4; ++ni)
                    acc[mi][ni] = __builtin_amdgcn_mfma_f32_16x16x32_bf16(
                        av[mi], bv[ni], acc[mi][ni], 0, 0, 0);
        }
    }

    // epilogue: write gates (bf16) + GN partial stats (fp32 from acc)
    float s1 = 0.f, s2 = 0.f;
    unsigned short* __restrict__ gbase = gatesb
        + ((size_t)dirb * 256 + (size_t)ocblk * 64) * PX;
#pragma unroll
    for (int mi = 0; mi < 4; ++mi)
#pragma unroll
        for (int ni = 0; ni < 4; ++ni) {
            int nr = ni >> 1, nc = ni & 1;
            int px = (py0 + 2 * w + nr) * 64 + pxc0 + nc * 16 + l15;
#pragma unroll
            for (int j = 0; j < 4; ++j) {
                float v = acc[mi][ni][j];
                int oc = mi * 16 + l4 * 4 + j;
                gbase[(size_t)oc * PX + px] = f2b(v);
                s1 += v;
                s2 += v * v;
            }
        }
    for (int off = 32; off; off >>= 1) {
        s1 += __shfl_down(s1, off);
        s2 += __shfl_down(s2, off);
    }
    if (l == 0) { red[w * 2] = s1; red[w * 2 + 1] = s2; }
    __syncthreads();
    if (tid == 0) {
        float a = red[0] + red[2] + red[4] + red[6];
        float q = red[1] + red[3] + red[5] + red[7];
        float* slot = gnstats + (((size_t)(s * 2 + dir) * 4 + b) * 4 + ocblk) * 2;
        atomicAdd(slot, a);
        atomicAdd(slot + 1, q);
    }
}

// K2: GN + activations + LSTM update; writes h (f32), c (f32), comb_t (bf16).
// idx bits: [dirb(3)][pxh(9)][o8(3)][pxl(3)]
__global__ __launch_bounds__(256) void point_kernel2(
    const unsigned short* __restrict__ gatesb, const float* __restrict__ gnstats,
    const float* __restrict__ gnf_w, const float* __restrict__ gnf_b,
    const float* __restrict__ gnb_w, const float* __restrict__ gnb_b,
    float* __restrict__ hbuf, float* __restrict__ cbuf,
    unsigned short* __restrict__ comb_t, int s)
{
    int idx = blockIdx.x * 256 + threadIdx.x;
    int pxl = idx & 7;
    int o8 = (idx >> 3) & 7;
    int pxh = (idx >> 6) & 511;
    int dirb = idx >> 15;
    int px = pxh * 8 + pxl;
    int dir = dirb >> 2, b = dirb & 3;

    __shared__ float gwl[256], gbl[256], mrs[8];
    int tid = threadIdx.x;
    {
        const float* __restrict__ gw = dir ? gnb_w : gnf_w;
        const float* __restrict__ gb = dir ? gnb_b : gnf_b;
        gwl[tid] = gw[tid];
        gbl[tid] = gb[tid];
    }
    if (tid < 4) {
        const float* slot = gnstats + ((size_t)(s * 2 + dir) * 4 + b) * 8 + tid * 2;
        const float invN = 1.0f / 262144.0f;
        float mean = slot[0] * invN;
        float var = slot[1] * invN - mean * mean;
        mrs[tid * 2] = mean;
        mrs[tid * 2 + 1] = rsqrtf(var + EPS);
    }
    __syncthreads();

    const unsigned short* __restrict__ gbase = gatesb + (size_t)dirb * 256 * PX + px;
    size_t hcbase = ((size_t)dirb * 64 + o8 * 8) * PX + px;
    float m0 = mrs[0], r0 = mrs[1], m1 = mrs[2], r1 = mrs[3];
    float m2 = mrs[4], r2 = mrs[5], m3 = mrs[6], r3 = mrs[7];

    unsigned int packed[4];
#pragma unroll
    for (int cc = 0; cc < 8; ++cc) {
        int ch = o8 * 8 + cc;
        float g0 = b2f(gbase[(size_t)(ch) * PX]);
        float g1 = b2f(gbase[(size_t)(64 + ch) * PX]);
        float g2 = b2f(gbase[(size_t)(128 + ch) * PX]);
        float g3 = b2f(gbase[(size_t)(192 + ch) * PX]);
        float v0 = (g0 - m0) * r0 * gwl[ch] + gbl[ch];
        float v1 = (g1 - m1) * r1 * gwl[64 + ch] + gbl[64 + ch];
        float v2 = (g2 - m2) * r2 * gwl[128 + ch] + gbl[128 + ch];
        float v3 = (g3 - m3) * r3 * gwl[192 + ch] + gbl[192 + ch];
        float ig = rcpf(1.f + __expf(-v0));
        float fg = rcpf(1.f + __expf(-v1));
        float og = rcpf(1.f + __expf(-v2));
        float gg = 1.f - 2.f * rcpf(1.f + __expf(2.f * v3));
        float cold = cbuf[hcbase + (size_t)cc * PX];
        float cnew = fg * cold + ig * gg;
        float th = 1.f - 2.f * rcpf(1.f + __expf(2.f * cnew));
        float hnew = og * th;
        cbuf[hcbase + (size_t)cc * PX] = cnew;
        hbuf[hcbase + (size_t)cc * PX] = hnew;
        unsigned int hb = (unsigned int)f2b(hnew);
        if (cc & 1) packed[cc >> 1] |= hb << 16;
        else        packed[cc >> 1] = hb;
    }
    int t = dir ? (15 - s) : s;
    size_t co = ((size_t)(t * 4 + b) * 4096 + px) * 128 + dir * 64 + o8 * 8;
    *reinterpret_cast<uint4*>(comb_t + co) =
        make_uint4(packed[0], packed[1], packed[2], packed[3]);
}

// K3: 1x1 fuse conv via MFMA; BN partial stats only.
// grid 1024: n = bid>>4, pxb = bid&15. block 256 (4 waves, 64 px each).
__global__ __launch_bounds__(256) void fuse_stats2_kernel(
    const unsigned short* __restrict__ comb_t,
    const unsigned short* __restrict__ wfrag, float* __restrict__ bnparts)
{
    int n = blockIdx.x >> 4, pxb = blockIdx.x & 15;
    int tid = threadIdx.x;
    int w = tid >> 6, l = tid & 63;
    int l15 = l & 15, l4 = l >> 4;

    bf16x8 B[4][4];
#pragma unroll
    for (int ocb = 0; ocb < 4; ++ocb)
#pragma unroll
        for (int icblk = 0; icblk < 4; ++icblk)
            B[ocb][icblk] = *reinterpret_cast<const bf16x8*>(
                wfrag + (((ocb * 4 + icblk) * 64 + l) * 8));

    f32x4 acc[4][4];
#pragma unroll
    for (int i = 0; i < 4; ++i)
#pragma unroll
        for (int j = 0; j < 4; ++j)
            acc[i][j] = (f32x4){0.f, 0.f, 0.f, 0.f};

    int px0 = pxb * 256 + w * 64;
    const unsigned short* __restrict__ cb = comb_t + (size_t)n * 4096 * 128;
#pragma unroll
    for (int ps = 0; ps < 4; ++ps) {
        const unsigned short* ab = cb + (size_t)(px0 + ps * 16 + l15) * 128 + l4 * 8;
        bf16x8 A[4];
#pragma unroll
        for (int icblk = 0; icblk < 4; ++icblk)
            A[icblk] = *reinterpret_cast<const bf16x8*>(ab + icblk * 32);
#pragma unroll
        for (int icblk = 0; icblk < 4; ++icblk)
#pragma unroll
            for (int ocb = 0; ocb < 4; ++ocb)
                acc[ps][ocb] = __builtin_amdgcn_mfma_f32_16x16x32_bf16(
                    A[icblk], B[ocb][icblk], acc[ps][ocb], 0, 0, 0);
    }

    float s1[4] = {0, 0, 0, 0}, s2[4] = {0, 0, 0, 0};
#pragma unroll
    for (int ps = 0; ps < 4; ++ps)
#pragma unroll
        for (int ocb = 0; ocb < 4; ++ocb)
#pragma unroll
            for (int j = 0; j < 4; ++j) {
                float v = acc[ps][ocb][j];
                s1[ocb] += v;
                s2[ocb] += v * v;
            }
#pragma unroll
    for (int ocb = 0; ocb < 4; ++ocb) {
        s1[ocb] += __shfl_down(s1[ocb], 32);
        s1[ocb] += __shfl_down(s1[ocb], 16);
        s2[ocb] += __shfl_down(s2[ocb], 32);
        s2[ocb] += __shfl_down(s2[ocb], 16);
    }
    __shared__ float sred[4][4][16][2];
    if (l < 16)
#pragma unroll
        for (int ocb = 0; ocb < 4; ++ocb) {
            sred[w][ocb][l][0] = s1[ocb];
            sred[w][ocb][l][1] = s2[ocb];
        }
    __syncthreads();
    if (tid < 128) {
        int oc = tid >> 1, isq = tid & 1;
        float v = sred[0][oc >> 4][oc & 15][isq] + sred[1][oc >> 4][oc & 15][isq]
                + sred[2][oc >> 4][oc & 15][isq] + sred[3][oc >> 4][oc & 15][isq];
        atomicAdd(bnparts + (blockIdx.x & 7) * 128 + tid, v);
    }
}

// K4: recompute fuse MFMA, BN + ReLU, transposed store to out.
__global__ __launch_bounds__(256) void bn_apply2_kernel(
    const unsigned short* __restrict__ comb_t,
    const unsigned short* __restrict__ wfrag, const float* __restrict__ bnparts,
    const float* __restrict__ bn_w, const float* __restrict__ bn_b,
    float* __restrict__ out)
{
    int n = blockIdx.x >> 4, pxb = blockIdx.x & 15;
    int tid = threadIdx.x;
    int w = tid >> 6, l = tid & 63;
    int l15 = l & 15, l4 = l >> 4;

    __shared__ float sc[64], sh[64];
    if (tid < 64) {
        const float invN = 1.0f / 262144.0f;
        float S = 0.f, Q = 0.f;
#pragma unroll
        for (int p = 0; p < 8; ++p) {
            S += bnparts[p * 128 + tid * 2];
            Q += bnparts[p * 128 + tid * 2 + 1];
        }
        float mean = S * invN;
        float var = Q * invN - mean * mean;
        float scale = rsqrtf(var + EPS) * bn_w[tid];
        sc[tid] = scale;
        sh[tid] = bn_b[tid] - mean * scale;
    }

    bf16x8 B[4][4];
#pragma unroll
    for (int ocb = 0; ocb < 4; ++ocb)
#pragma unroll
        for (int icblk = 0; icblk < 4; ++icblk)
            B[ocb][icblk] = *reinterpret_cast<const bf16x8*>(
                wfrag + (((ocb * 4 + icblk) * 64 + l) * 8));
    __syncthreads();

    f32x4 acc[4][4];
#pragma unroll
    for (int i = 0; i < 4; ++i)
#pragma unroll
        for (int j = 0; j < 4; ++j)
            acc[i][j] = (f32x4){0.f, 0.f, 0.f, 0.f};

    int px0 = pxb * 256 + w * 64;
    const unsigned short* __restrict__ cb = comb_t + (size_t)n * 4096 * 128;
#pragma unroll
    for (int ps = 0; ps < 4; ++ps) {
        const unsigned short* ab = cb + (size_t)(px0 + ps * 16 + l15) * 128 + l4 * 8;
        bf16x8 A[4];
#pragma unroll
        for (int icblk = 0; icblk < 4; ++icblk)
            A[icblk] = *reinterpret_cast<const bf16x8*>(ab + icblk * 32);
#pragma unroll
        for (int icblk = 0; icblk < 4; ++icblk)
#pragma unroll
            for (int ocb = 0; ocb < 4; ++ocb)
                acc[ps][ocb] = __builtin_amdgcn_mfma_f32_16x16x32_bf16(
                    A[icblk], B[ocb][icblk], acc[ps][ocb], 0, 0, 0);
    }

    int t = n >> 2, bb = n & 3;
#pragma unroll
    for (int ps = 0; ps < 4; ++ps)
#pragma unroll
        for (int ocb = 0; ocb < 4; ++ocb) {
            int oc = ocb * 16 + l15;
            float scale = sc[oc], shift = sh[oc];
            float4 v;
            v.x = fmaxf(acc[ps][ocb][0] * scale + shift, 0.f);
            v.y = fmaxf(acc[ps][ocb][1] * scale + shift, 0.f);
            v.z = fmaxf(acc[ps][ocb][2] * scale + shift, 0.f);
            v.w = fmaxf(acc[ps][ocb][3] * scale + shift, 0.f);
            float* op = out + ((size_t)((bb * 16 + t) * 64 + oc)) * PX
                      + px0 + ps * 16 + l4 * 4;
            *reinterpret_cast<float4*>(op) = v;
        }
}

extern "C" void kernel_launch(void* const* d_in, const int* in_sizes, int n_in,
                              void* d_out, int out_size, void* d_ws, size_t ws_size,
                              hipStream_t stream) {
    const float* x     = (const float*)d_in[0];
    const float* Wf    = (const float*)d_in[1];
    const float* gnf_w = (const float*)d_in[2];
    const float* gnf_b = (const float*)d_in[3];
    const float* Wb    = (const float*)d_in[4];
    const float* gnb_w = (const float*)d_in[5];
    const float* gnb_b = (const float*)d_in[6];
    const float* Wfu   = (const float*)d_in[7];
    const float* bn_w  = (const float*)d_in[8];
    const float* bn_b  = (const float*)d_in[9];
    float* out = (float*)d_out;

    float* ws = (float*)d_ws;
    unsigned short* comb_t = (unsigned short*)ws;               // 16,777,216 f
    unsigned short* gatesb = (unsigned short*)(ws + 16777216);  //  4,194,304 f
    float* hbuf    = ws + 16777216 + 4194304;                   //  2,097,152 f
    float* cbuf    = hbuf + 2097152;                            //  2,097,152 f
    float* gnstats = cbuf + 2097152;                            //      1,024 f
    float* bnparts = gnstats + 1024;                            //      1,024 f
    unsigned short* W2    = (unsigned short*)(bnparts + 1024);  //    294,912 f
    unsigned short* wfrag = (unsigned short*)(bnparts + 1024 + 294912); // 4,096 f

    // zero h, c, gn stats, bn partials (contiguous)
    hipMemsetAsync(hbuf, 0, (size_t)(2097152ll * 2 + 2048) * 4, stream);

    wconv_kernel<<<2304, 256, 0, stream>>>(Wf, Wb, W2);
    wfu_pack_kernel<<<32, 256, 0, stream>>>(Wfu, wfrag);

    for (int s = 0; s < 16; ++s) {
        conv_mfma_kernel<<<dim3(64, 8), 256, 0, stream>>>(
            x, hbuf, W2, gatesb, gnstats, s);
        point_kernel2<<<1024, 256, 0, stream>>>(
            gatesb, gnstats, gnf_w, gnf_b, gnb_w, gnb_b, hbuf, cbuf, comb_t, s);
    }
    fuse_stats2_kernel<<<1024, 256, 0, stream>>>(comb_t, wfrag, bnparts);
    bn_apply2_kernel<<<1024, 256, 0, stream>>>(comb_t, wfrag, bnparts, bn_w, bn_b, out);
}

// Round 5
// 653.773 us; speedup vs baseline: 11.0054x; 1.8671x over previous
//
#include <hip/hip_runtime.h>
#include <math.h>

#define PX 4096         // 64*64 spatial
#define EPS 1e-5f

typedef __attribute__((ext_vector_type(8))) __bf16 bf16x8;
typedef __attribute__((ext_vector_type(4))) float f32x4;

static __device__ __forceinline__ unsigned short f2b(float f) {
    unsigned int u = __float_as_uint(f);
    u += 0x7FFFu + ((u >> 16) & 1u);     // RTNE
    return (unsigned short)(u >> 16);
}
static __device__ __forceinline__ float b2f(unsigned short u) {
    return __uint_as_float((unsigned int)u << 16);
}
static __device__ __forceinline__ float rcpf(float x) {
    return __builtin_amdgcn_rcpf(x);
}

// ---------------------------------------------------------------------------
// ws layout (float units):
//   comb_t  bf16 [64 n][4096 px][128 ic]          16,777,216 f  @ 0
//   gatesb  bf16 [8 dirb][256 oc][4096 px]         4,194,304 f  @ 16,777,216
//   cbuf    f32  [8 dirb][64 ch][4096]             2,097,152 f  @ 20,971,520
//   gnstat  f32  [16 s][2 dir][4 b][4 g][2]            1,024 f  @ 23,068,672
//   bnparts f32  [8 part][64 oc][2]                    1,024 f  @ 23,069,696
//   W2s     bf16 [dir][ocblk][icblk][tap][64][4][8] 294,912 f  @ 23,070,720
//   wfrag   bf16 [4 ocb][4 icblk][64 l][8 j]           4,096 f  @ 23,365,632
//   xb      bf16 [64 bt][4096 px][64 ic]            8,388,608 f @ 23,369,728
// ---------------------------------------------------------------------------

// Pack conv weights bf16, pre-swizzled to the conv kernel's LDS image.
__global__ __launch_bounds__(256) void wconv2_kernel(
    const float* __restrict__ Wf, const float* __restrict__ Wb,
    unsigned short* __restrict__ W2s)
{
    int idx = blockIdx.x * 256 + threadIdx.x;
    if (idx >= 589824) return;
    int within = idx & 2047;
    int grp = idx >> 11;
    int oc = within >> 5;
    int slot = (within >> 3) & 3;
    int j = within & 7;
    int tap = grp % 9;
    int rest = grp / 9;
    int icblk = rest & 3;
    int ocblk = (rest >> 2) & 3;
    int dir = rest >> 4;
    int c = slot ^ ((oc >> 1) & 3);
    int ic = icblk * 32 + c * 8 + j;
    int OC = ocblk * 64 + oc;
    const float* __restrict__ W = dir ? Wb : Wf;
    W2s[idx] = f2b(W[((size_t)OC * 128 + ic) * 9 + tap]);
}

// Pack Wfu into MFMA B-fragment order: [ocb][icblk][lane][j]
__global__ __launch_bounds__(256) void wfu_pack_kernel(
    const float* __restrict__ Wfu, unsigned short* __restrict__ wfrag)
{
    int idx = blockIdx.x * 256 + threadIdx.x;
    if (idx >= 8192) return;
    int j = idx & 7;
    int l = (idx >> 3) & 63;
    int icblk = (idx >> 9) & 3;
    int ocb = idx >> 11;
    int oc = ocb * 16 + (l & 15);
    int ic = icblk * 32 + (l >> 4) * 8 + j;
    wfrag[idx] = f2b(Wfu[oc * 128 + ic]);
}

// Transpose x to px-major bf16: xb[bt][px][64 ic].
// grid: bt(64) x pxblk(64). block 256. LDS 64px x 72ic tile.
__global__ __launch_bounds__(256) void xconv_kernel(
    const float* __restrict__ x, unsigned short* __restrict__ xb)
{
    int bt = blockIdx.x >> 6;
    int px0 = (blockIdx.x & 63) * 64;
    __shared__ unsigned short sh[64 * 72];
    int tid = threadIdx.x;
    {
        int px_l = tid & 63;
        int ic4 = tid >> 6;
        const float* __restrict__ src = x + (size_t)bt * 64 * PX + px0 + px_l;
#pragma unroll
        for (int k = 0; k < 16; ++k) {
            int ic = ic4 * 16 + k;
            sh[px_l * 72 + ic] = f2b(src[(size_t)ic * PX]);
        }
    }
    __syncthreads();
    {
        int px_w = tid >> 2;
        int ch = tid & 3;
        // each thread covers 16 consecutive ic = 2 x uint4 (fix of R4 bug:
        // previously only the first uint4 was written -> half of xb poisoned)
        uint4 v0 = *reinterpret_cast<const uint4*>(&sh[px_w * 72 + ch * 16]);
        uint4 v1 = *reinterpret_cast<const uint4*>(&sh[px_w * 72 + ch * 16 + 8]);
        unsigned short* dst = xb + ((size_t)bt * PX + px0 + px_w) * 64 + ch * 16;
        *reinterpret_cast<uint4*>(dst) = v0;
        *reinterpret_cast<uint4*>(dst + 8) = v1;
    }
}

// K1: implicit-GEMM conv via MFMA. Staging = pure uint4 copies.
// grid x = ocblk(4)*pxtile(16) = 64, y = dirb(8). block = 256 (4 waves).
__global__ __launch_bounds__(256) void conv_mfma_kernel(
    const unsigned short* __restrict__ xb, const unsigned short* __restrict__ comb_t,
    const unsigned short* __restrict__ W2s,
    unsigned short* __restrict__ gatesb, float* __restrict__ gnstats, int s)
{
    const int dirb = blockIdx.y;
    const int dir = dirb >> 2, b = dirb & 3;
    const int ocblk = blockIdx.x >> 4;
    const int pxt = blockIdx.x & 15;
    const int py0 = (pxt >> 1) * 8;
    const int pxc0 = (pxt & 1) * 32;
    const int t = dir ? (15 - s) : s;
    const int prev_t = dir ? (t + 1) : (t - 1);

    __shared__ __align__(16) unsigned short Wl[9 * 64 * 32];   // 36,864 B
    __shared__ __align__(16) unsigned short in_s[340 * 32];    // 21,760 B
    __shared__ float red[8];

    const int tid = threadIdx.x;
    const int w = tid >> 6;
    const int l = tid & 63;
    const int l15 = l & 15;
    const int l4 = l >> 4;

    const unsigned short* __restrict__ xpx = xb + (size_t)(b * 16 + t) * PX * 64;
    const unsigned short* __restrict__ hpx = comb_t
        + (size_t)(prev_t * 4 + b) * PX * 128 + dir * 64;

    f32x4 acc[4][4];
#pragma unroll
    for (int i = 0; i < 4; ++i)
#pragma unroll
        for (int j = 0; j < 4; ++j)
            acc[i][j] = (f32x4){0.f, 0.f, 0.f, 0.f};

    for (int icblk = 0; icblk < 4; ++icblk) {
        __syncthreads();
        // ---- stage weights: straight 36,864-B copy (pre-swizzled)
        {
            const unsigned short* __restrict__ wsrc = W2s
                + ((size_t)((dir * 4 + ocblk) * 4 + icblk) * 9) * 2048;
#pragma unroll
            for (int it = 0; it < 9; ++it) {
                int e = tid + it * 256;
                *reinterpret_cast<uint4*>(&Wl[e * 8]) =
                    *reinterpret_cast<const uint4*>(wsrc + e * 8);
            }
        }
        // ---- stage input halo tile: 340 px x 32 ic (uint4 per lane)
        {
            const bool useh = icblk >= 2;
            const unsigned short* __restrict__ srcpx = useh
                ? (hpx + (icblk - 2) * 32) : (xpx + icblk * 32);
            const int rec = useh ? 128 : 64;
            const bool zero = useh && (s == 0);
#pragma unroll
            for (int it = 0; it < 6; ++it) {
                int idx = tid + it * 256;
                if (idx < 1360) {
                    int c = idx & 3;
                    int pl = idx >> 2;
                    int row = (pl * 241) >> 13;      // pl / 34
                    int col = pl - row * 34;
                    int gy = py0 - 1 + row;
                    int gx = pxc0 - 1 + col;
                    bool valid = ((unsigned)gy < 64u) && ((unsigned)gx < 64u) && !zero;
                    uint4 v = make_uint4(0u, 0u, 0u, 0u);
                    if (valid)
                        v = *reinterpret_cast<const uint4*>(
                            srcpx + (size_t)(gy * 64 + gx) * rec + c * 8);
                    int woff = pl * 32 + ((c ^ ((pl >> 1) & 3)) * 8);
                    *reinterpret_cast<uint4*>(&in_s[woff]) = v;
                }
            }
        }
        __syncthreads();

        // ---- 9 taps x 16 MFMA
#pragma unroll
        for (int tap = 0; tap < 9; ++tap) {
            const int dy = tap / 3, dx = tap % 3;
            bf16x8 av[4], bv[4];
#pragma unroll
            for (int mi = 0; mi < 4; ++mi) {
                int oc = mi * 16 + l15;
                int aoff = tap * 2048 + oc * 32 + ((l4 ^ ((oc >> 1) & 3)) * 8);
                av[mi] = *reinterpret_cast<const bf16x8*>(&Wl[aoff]);
            }
#pragma unroll
            for (int ni = 0; ni < 4; ++ni) {
                int nr = ni >> 1, nc = ni & 1;
                int pl = (2 * w + nr + dy) * 34 + nc * 16 + l15 + dx;
                int boff = pl * 32 + ((l4 ^ ((pl >> 1) & 3)) * 8);
                bv[ni] = *reinterpret_cast<const bf16x8*>(&in_s[boff]);
            }
#pragma unroll
            for (int mi = 0; mi < 4; ++mi)
#pragma unroll
                for (int ni = 0; ni < 4; ++ni)
                    acc[mi][ni] = __builtin_amdgcn_mfma_f32_16x16x32_bf16(
                        av[mi], bv[ni], acc[mi][ni], 0, 0, 0);
        }
    }

    // epilogue: write gates (bf16) + GN partial stats (fp32 from acc)
    float s1 = 0.f, s2 = 0.f;
    unsigned short* __restrict__ gbase = gatesb
        + ((size_t)dirb * 256 + (size_t)ocblk * 64) * PX;
#pragma unroll
    for (int mi = 0; mi < 4; ++mi)
#pragma unroll
        for (int ni = 0; ni < 4; ++ni) {
            int nr = ni >> 1, nc = ni & 1;
            int px = (py0 + 2 * w + nr) * 64 + pxc0 + nc * 16 + l15;
#pragma unroll
            for (int j = 0; j < 4; ++j) {
                float v = acc[mi][ni][j];
                int oc = mi * 16 + l4 * 4 + j;
                gbase[(size_t)oc * PX + px] = f2b(v);
                s1 += v;
                s2 += v * v;
            }
        }
    for (int off = 32; off; off >>= 1) {
        s1 += __shfl_down(s1, off);
        s2 += __shfl_down(s2, off);
    }
    if (l == 0) { red[w * 2] = s1; red[w * 2 + 1] = s2; }
    __syncthreads();
    if (tid == 0) {
        float a = red[0] + red[2] + red[4] + red[6];
        float q = red[1] + red[3] + red[5] + red[7];
        float* slot = gnstats + (((size_t)(s * 2 + dir) * 4 + b) * 4 + ocblk) * 2;
        atomicAdd(slot, a);
        atomicAdd(slot + 1, q);
    }
}

// K2: GN + activations + LSTM update; writes c (f32), comb_t (bf16).
__global__ __launch_bounds__(256) void point_kernel2(
    const unsigned short* __restrict__ gatesb, const float* __restrict__ gnstats,
    const float* __restrict__ gnf_w, const float* __restrict__ gnf_b,
    const float* __restrict__ gnb_w, const float* __restrict__ gnb_b,
    float* __restrict__ cbuf, unsigned short* __restrict__ comb_t, int s)
{
    int idx = blockIdx.x * 256 + threadIdx.x;
    int pxl = idx & 7;
    int o8 = (idx >> 3) & 7;
    int pxh = (idx >> 6) & 511;
    int dirb = idx >> 15;
    int px = pxh * 8 + pxl;
    int dir = dirb >> 2, b = dirb & 3;

    __shared__ float gwl[256], gbl[256], mrs[8];
    int tid = threadIdx.x;
    {
        const float* __restrict__ gw = dir ? gnb_w : gnf_w;
        const float* __restrict__ gb = dir ? gnb_b : gnf_b;
        gwl[tid] = gw[tid];
        gbl[tid] = gb[tid];
    }
    if (tid < 4) {
        const float* slot = gnstats + ((size_t)(s * 2 + dir) * 4 + b) * 8 + tid * 2;
        const float invN = 1.0f / 262144.0f;
        float mean = slot[0] * invN;
        float var = slot[1] * invN - mean * mean;
        mrs[tid * 2] = mean;
        mrs[tid * 2 + 1] = rsqrtf(var + EPS);
    }
    __syncthreads();

    const unsigned short* __restrict__ gbase = gatesb + (size_t)dirb * 256 * PX + px;
    size_t cbase = ((size_t)dirb * 64 + o8 * 8) * PX + px;
    float m0 = mrs[0], r0 = mrs[1], m1 = mrs[2], r1 = mrs[3];
    float m2 = mrs[4], r2 = mrs[5], m3 = mrs[6], r3 = mrs[7];

    unsigned int packed[4];
#pragma unroll
    for (int cc = 0; cc < 8; ++cc) {
        int ch = o8 * 8 + cc;
        float g0 = b2f(gbase[(size_t)(ch) * PX]);
        float g1 = b2f(gbase[(size_t)(64 + ch) * PX]);
        float g2 = b2f(gbase[(size_t)(128 + ch) * PX]);
        float g3 = b2f(gbase[(size_t)(192 + ch) * PX]);
        float v0 = (g0 - m0) * r0 * gwl[ch] + gbl[ch];
        float v1 = (g1 - m1) * r1 * gwl[64 + ch] + gbl[64 + ch];
        float v2 = (g2 - m2) * r2 * gwl[128 + ch] + gbl[128 + ch];
        float v3 = (g3 - m3) * r3 * gwl[192 + ch] + gbl[192 + ch];
        float ig = rcpf(1.f + __expf(-v0));
        float fg = rcpf(1.f + __expf(-v1));
        float og = rcpf(1.f + __expf(-v2));
        float gg = 1.f - 2.f * rcpf(1.f + __expf(2.f * v3));
        float cold = cbuf[cbase + (size_t)cc * PX];
        float cnew = fg * cold + ig * gg;
        float th = 1.f - 2.f * rcpf(1.f + __expf(2.f * cnew));
        float hnew = og * th;
        cbuf[cbase + (size_t)cc * PX] = cnew;
        unsigned int hb = (unsigned int)f2b(hnew);
        if (cc & 1) packed[cc >> 1] |= hb << 16;
        else        packed[cc >> 1] = hb;
    }
    int t = dir ? (15 - s) : s;
    size_t co = ((size_t)(t * 4 + b) * PX + px) * 128 + dir * 64 + o8 * 8;
    *reinterpret_cast<uint4*>(comb_t + co) =
        make_uint4(packed[0], packed[1], packed[2], packed[3]);
}

// K3: 1x1 fuse conv via MFMA; BN partial stats only.
__global__ __launch_bounds__(256) void fuse_stats2_kernel(
    const unsigned short* __restrict__ comb_t,
    const unsigned short* __restrict__ wfrag, float* __restrict__ bnparts)
{
    int n = blockIdx.x >> 4, pxb = blockIdx.x & 15;
    int tid = threadIdx.x;
    int w = tid >> 6, l = tid & 63;
    int l15 = l & 15, l4 = l >> 4;

    bf16x8 B[4][4];
#pragma unroll
    for (int ocb = 0; ocb < 4; ++ocb)
#pragma unroll
        for (int icblk = 0; icblk < 4; ++icblk)
            B[ocb][icblk] = *reinterpret_cast<const bf16x8*>(
                wfrag + (((ocb * 4 + icblk) * 64 + l) * 8));

    f32x4 acc[4][4];
#pragma unroll
    for (int i = 0; i < 4; ++i)
#pragma unroll
        for (int j = 0; j < 4; ++j)
            acc[i][j] = (f32x4){0.f, 0.f, 0.f, 0.f};

    int px0 = pxb * 256 + w * 64;
    const unsigned short* __restrict__ cb = comb_t + (size_t)n * PX * 128;
#pragma unroll
    for (int ps = 0; ps < 4; ++ps) {
        const unsigned short* ab = cb + (size_t)(px0 + ps * 16 + l15) * 128 + l4 * 8;
        bf16x8 A[4];
#pragma unroll
        for (int icblk = 0; icblk < 4; ++icblk)
            A[icblk] = *reinterpret_cast<const bf16x8*>(ab + icblk * 32);
#pragma unroll
        for (int icblk = 0; icblk < 4; ++icblk)
#pragma unroll
            for (int ocb = 0; ocb < 4; ++ocb)
                acc[ps][ocb] = __builtin_amdgcn_mfma_f32_16x16x32_bf16(
                    A[icblk], B[ocb][icblk], acc[ps][ocb], 0, 0, 0);
    }

    float s1[4] = {0, 0, 0, 0}, s2[4] = {0, 0, 0, 0};
#pragma unroll
    for (int ps = 0; ps < 4; ++ps)
#pragma unroll
        for (int ocb = 0; ocb < 4; ++ocb)
#pragma unroll
            for (int j = 0; j < 4; ++j) {
                float v = acc[ps][ocb][j];
                s1[ocb] += v;
                s2[ocb] += v * v;
            }
#pragma unroll
    for (int ocb = 0; ocb < 4; ++ocb) {
        s1[ocb] += __shfl_down(s1[ocb], 32);
        s1[ocb] += __shfl_down(s1[ocb], 16);
        s2[ocb] += __shfl_down(s2[ocb], 32);
        s2[ocb] += __shfl_down(s2[ocb], 16);
    }
    __shared__ float sred[4][4][16][2];
    if (l < 16)
#pragma unroll
        for (int ocb = 0; ocb < 4; ++ocb) {
            sred[w][ocb][l][0] = s1[ocb];
            sred[w][ocb][l][1] = s2[ocb];
        }
    __syncthreads();
    if (tid < 128) {
        int oc = tid >> 1, isq = tid & 1;
        float v = sred[0][oc >> 4][oc & 15][isq] + sred[1][oc >> 4][oc & 15][isq]
                + sred[2][oc >> 4][oc & 15][isq] + sred[3][oc >> 4][oc & 15][isq];
        atomicAdd(bnparts + (blockIdx.x & 7) * 128 + tid, v);
    }
}

// K4: recompute fuse MFMA, BN + ReLU, transposed store to out.
__global__ __launch_bounds__(256) void bn_apply2_kernel(
    const unsigned short* __restrict__ comb_t,
    const unsigned short* __restrict__ wfrag, const float* __restrict__ bnparts,
    const float* __restrict__ bn_w, const float* __restrict__ bn_b,
    float* __restrict__ out)
{
    int n = blockIdx.x >> 4, pxb = blockIdx.x & 15;
    int tid = threadIdx.x;
    int w = tid >> 6, l = tid & 63;
    int l15 = l & 15, l4 = l >> 4;

    __shared__ float sc[64], sh[64];
    if (tid < 64) {
        const float invN = 1.0f / 262144.0f;
        float S = 0.f, Q = 0.f;
#pragma unroll
        for (int p = 0; p < 8; ++p) {
            S += bnparts[p * 128 + tid * 2];
            Q += bnparts[p * 128 + tid * 2 + 1];
        }
        float mean = S * invN;
        float var = Q * invN - mean * mean;
        float scale = rsqrtf(var + EPS) * bn_w[tid];
        sc[tid] = scale;
        sh[tid] = bn_b[tid] - mean * scale;
    }

    bf16x8 B[4][4];
#pragma unroll
    for (int ocb = 0; ocb < 4; ++ocb)
#pragma unroll
        for (int icblk = 0; icblk < 4; ++icblk)
            B[ocb][icblk] = *reinterpret_cast<const bf16x8*>(
                wfrag + (((ocb * 4 + icblk) * 64 + l) * 8));
    __syncthreads();

    f32x4 acc[4][4];
#pragma unroll
    for (int i = 0; i < 4; ++i)
#pragma unroll
        for (int j = 0; j < 4; ++j)
            acc[i][j] = (f32x4){0.f, 0.f, 0.f, 0.f};

    int px0 = pxb * 256 + w * 64;
    const unsigned short* __restrict__ cb = comb_t + (size_t)n * PX * 128;
#pragma unroll
    for (int ps = 0; ps < 4; ++ps) {
        const unsigned short* ab = cb + (size_t)(px0 + ps * 16 + l15) * 128 + l4 * 8;
        bf16x8 A[4];
#pragma unroll
        for (int icblk = 0; icblk < 4; ++icblk)
            A[icblk] = *reinterpret_cast<const bf16x8*>(ab + icblk * 32);
#pragma unroll
        for (int icblk = 0; icblk < 4; ++icblk)
#pragma unroll
            for (int ocb = 0; ocb < 4; ++ocb)
                acc[ps][ocb] = __builtin_amdgcn_mfma_f32_16x16x32_bf16(
                    A[icblk], B[ocb][icblk], acc[ps][ocb], 0, 0, 0);
    }

    int t = n >> 2, bb = n & 3;
#pragma unroll
    for (int ps = 0; ps < 4; ++ps)
#pragma unroll
        for (int ocb = 0; ocb < 4; ++ocb) {
            int oc = ocb * 16 + l15;
            float scale = sc[oc], shift = sh[oc];
            float4 v;
            v.x = fmaxf(acc[ps][ocb][0] * scale + shift, 0.f);
            v.y = fmaxf(acc[ps][ocb][1] * scale + shift, 0.f);
            v.z = fmaxf(acc[ps][ocb][2] * scale + shift, 0.f);
            v.w = fmaxf(acc[ps][ocb][3] * scale + shift, 0.f);
            float* op = out + ((size_t)((bb * 16 + t) * 64 + oc)) * PX
                      + px0 + ps * 16 + l4 * 4;
            *reinterpret_cast<float4*>(op) = v;
        }
}

extern "C" void kernel_launch(void* const* d_in, const int* in_sizes, int n_in,
                              void* d_out, int out_size, void* d_ws, size_t ws_size,
                              hipStream_t stream) {
    const float* x     = (const float*)d_in[0];
    const float* Wf    = (const float*)d_in[1];
    const float* gnf_w = (const float*)d_in[2];
    const float* gnf_b = (const float*)d_in[3];
    const float* Wb    = (const float*)d_in[4];
    const float* gnb_w = (const float*)d_in[5];
    const float* gnb_b = (const float*)d_in[6];
    const float* Wfu   = (const float*)d_in[7];
    const float* bn_w  = (const float*)d_in[8];
    const float* bn_b  = (const float*)d_in[9];
    float* out = (float*)d_out;

    float* ws = (float*)d_ws;
    unsigned short* comb_t = (unsigned short*)ws;               // 16,777,216 f
    unsigned short* gatesb = (unsigned short*)(ws + 16777216);  //  4,194,304 f
    float* cbuf    = ws + 20971520;                             //  2,097,152 f
    float* gnstats = ws + 23068672;                             //      1,024 f
    float* bnparts = ws + 23069696;                             //      1,024 f
    unsigned short* W2s   = (unsigned short*)(ws + 23070720);   //    294,912 f
    unsigned short* wfrag = (unsigned short*)(ws + 23365632);   //      4,096 f
    unsigned short* xb    = (unsigned short*)(ws + 23369728);   //  8,388,608 f

    // zero c, gn stats, bn partials (contiguous)
    hipMemsetAsync(cbuf, 0, (size_t)(2097152ll + 2048) * 4, stream);

    wconv2_kernel<<<2304, 256, 0, stream>>>(Wf, Wb, W2s);
    wfu_pack_kernel<<<32, 256, 0, stream>>>(Wfu, wfrag);
    xconv_kernel<<<4096, 256, 0, stream>>>(x, xb);

    for (int s = 0; s < 16; ++s) {
        conv_mfma_kernel<<<dim3(64, 8), 256, 0, stream>>>(
            xb, comb_t, W2s, gatesb, gnstats, s);
        point_kernel2<<<1024, 256, 0, stream>>>(
            gatesb, gnstats, gnf_w, gnf_b, gnb_w, gnb_b, cbuf, comb_t, s);
    }
    fuse_stats2_kernel<<<1024, 256, 0, stream>>>(comb_t, wfrag, bnparts);
    bn_apply2_kernel<<<1024, 256, 0, stream>>>(comb_t, wfrag, bnparts, bn_w, bn_b, out);
}